// Round 9
// baseline (248.157 us; speedup 1.0000x reference)
//
#include <hip/hip_runtime.h>

typedef unsigned short u16;
typedef unsigned int u32;
typedef short s16x8 __attribute__((ext_vector_type(8)));
typedef short s16x4 __attribute__((ext_vector_type(4)));
typedef float f32x4 __attribute__((ext_vector_type(4)));
typedef u32 u32x2 __attribute__((ext_vector_type(2)));

#define AS1 __attribute__((address_space(1)))
#define AS3 __attribute__((address_space(3)))

__device__ __forceinline__ float bf2f(u16 u) {
    union { unsigned int i; float f; } x; x.i = ((unsigned int)u) << 16; return x.f;
}
__device__ __forceinline__ u16 f2bf(float f) {
    union { float f; unsigned int i; } x; x.f = f;
    unsigned int r = (x.i + 0x7FFFu + ((x.i >> 16) & 1u)) >> 16;
    return (u16)r;
}
__device__ __forceinline__ void storeOut(u16* p, float v) { *p = f2bf(v); }
__device__ __forceinline__ void storeOut(float* p, float v) { *p = v; }
__device__ __forceinline__ float loadIn(const void* p, size_t i, int isf32) {
    return isf32 ? ((const float*)p)[i] : bf2f(((const u16*)p)[i]);
}
__device__ __forceinline__ float fexp2(float x) {
#if __has_builtin(__builtin_amdgcn_exp2f)
    return __builtin_amdgcn_exp2f(x);
#else
    return exp2f(x);
#endif
}
__device__ __forceinline__ u32 pack_bf(float a, float b) {
    u32 ua = __float_as_uint(a) + 0x8000u;
    u32 ub = __float_as_uint(b) + 0x8000u;
    return __builtin_amdgcn_perm(ub, ua, 0x07060302u);
}

// ---------------- runtime dtype detector ---------------------------------------------
__global__ __launch_bounds__(256) void detect_dtype(const u16* __restrict__ x,
                                                    int* __restrict__ flag) {
    __shared__ int cnt[4];
    const int tid = threadIdx.x;
    int c = 0;
    #pragma unroll
    for (int i = 0; i < 4; ++i) {
        const u16 u = x[tid * 4 + i];
        const int e = (u >> 7) & 0xFF;
        c += (e >= 101 && e <= 135) ? 1 : 0;
    }
    #pragma unroll
    for (int m = 1; m < 64; m <<= 1) c += __shfl_xor(c, m, 64);
    if ((tid & 63) == 0) cnt[tid >> 6] = c;
    __syncthreads();
    if (tid == 0) {
        const int t = cnt[0] + cnt[1] + cnt[2] + cnt[3];
        *flag = (t < 800) ? 1 : 0;
    }
}

// ---------------- cond @ w_cond -------------------------------------------------------
__global__ __launch_bounds__(256) void cond_gemv(const void* __restrict__ cond,
                                                 const void* __restrict__ w,
                                                 float* __restrict__ out,
                                                 const int* __restrict__ flag) {
    const int isf32 = *flag;
    const int d  = blockIdx.x * 256 + threadIdx.x;
    const int n  = blockIdx.y;
    const int k0 = blockIdx.z * 64;
    float acc = 0.f;
    #pragma unroll 8
    for (int k = 0; k < 64; ++k)
        acc += loadIn(cond, n * 1024 + k0 + k, isf32) *
               loadIn(w, (size_t)(k0 + k) * 1024 + d, isf32);
    atomicAdd(out + n * 1024 + d, acc);
}

// ---------------- RMS norm of x -------------------------------------------------------
__global__ __launch_bounds__(256) void rmsnorm_x(const void* __restrict__ x,
                                                 const float* __restrict__ scl,
                                                 u16* __restrict__ xn,
                                                 const int* __restrict__ flag) {
    const int isf32 = *flag;
    const int tok = blockIdx.x;
    const int n = tok >> 11;
    u16* orow = xn + (size_t)tok * 1024;
    const int base = threadIdx.x * 4;
    float f0, f1, f2, f3;
    if (isf32) {
        const float4 v = *(const float4*)((const float*)x + (size_t)tok * 1024 + base);
        f0 = v.x; f1 = v.y; f2 = v.z; f3 = v.w;
    } else {
        s16x4 uv = *(const s16x4*)((const u16*)x + (size_t)tok * 1024 + base);
        f0 = bf2f((u16)uv[0]); f1 = bf2f((u16)uv[1]); f2 = bf2f((u16)uv[2]); f3 = bf2f((u16)uv[3]);
    }
    float ss = f0 * f0 + f1 * f1 + f2 * f2 + f3 * f3;
    #pragma unroll
    for (int m = 1; m < 64; m <<= 1) ss += __shfl_xor(ss, m, 64);
    __shared__ float red[4];
    const int wave = threadIdx.x >> 6, lane = threadIdx.x & 63;
    if (lane == 0) red[wave] = ss;
    __syncthreads();
    float ms = (red[0] + red[1] + red[2] + red[3]) * (1.f / 1024.f);
    float rinv = rsqrtf(ms + 1e-6f);
    orow[base + 0] = f2bf(f0 * (scl[n * 1024 + base + 0] + 1.f) * rinv);
    orow[base + 1] = f2bf(f1 * (scl[n * 1024 + base + 1] + 1.f) * rinv);
    orow[base + 2] = f2bf(f2 * (scl[n * 1024 + base + 2] + 1.f) * rinv);
    orow[base + 3] = f2bf(f3 * (scl[n * 1024 + base + 3] + 1.f) * rinv);
}

// ---------------- transpose (R x C -> C x R) -----------------------------------------
__global__ __launch_bounds__(256) void transpose_bf(const void* __restrict__ src,
                                                    u16* __restrict__ dst, int R, int C,
                                                    const int* __restrict__ flag) {
    const int isf32 = *flag;
    __shared__ u16 t[32][33];
    const int c0 = blockIdx.x * 32, r0 = blockIdx.y * 32;
    const int tx = threadIdx.x & 31, ty = threadIdx.x >> 5;
    #pragma unroll
    for (int i = 0; i < 4; ++i)
        t[ty + i * 8][tx] = f2bf(loadIn(src, (size_t)(r0 + ty + i * 8) * C + c0 + tx, isf32));
    __syncthreads();
    #pragma unroll
    for (int i = 0; i < 4; ++i)
        dst[(size_t)(c0 + ty + i * 8) * R + r0 + tx] = t[tx][ty + i * 8];
}

// ---------------- bf16 GEMM 128x128, BK=32 -------------------------------------------
template <typename OutT>
__global__ __launch_bounds__(256) void gemm_bt(const u16* __restrict__ A,
                                               const u16* __restrict__ BT,
                                               OutT* __restrict__ C, int Nn, int K) {
    __shared__ u16 As[128 * 32];
    __shared__ u16 Bs[128 * 32];
    const int tid = threadIdx.x;
    const int wave = tid >> 6, lane = tid & 63;
    const int l15 = lane & 15, quad = lane >> 4;
    const int bm0 = blockIdx.y * 128, bn0 = blockIdx.x * 128;
    const int wr = wave >> 1, wc = wave & 1;
    f32x4 acc[4][4] = {};
    const int srow = lane >> 2;
    const int g = (lane & 3) ^ (srow & 3);
    for (int bk = 0; bk < K; bk += 32) {
        __syncthreads();
        #pragma unroll
        for (int p = 0; p < 2; ++p) {
            const int rowl = p * 64 + wave * 16 + srow;
            __builtin_amdgcn_global_load_lds(
                (const AS1 void*)(A + (size_t)(bm0 + rowl) * K + bk + g * 8),
                (AS3 void*)(As + (p * 64 + wave * 16) * 32), 16, 0, 0);
            __builtin_amdgcn_global_load_lds(
                (const AS1 void*)(BT + (size_t)(bn0 + rowl) * K + bk + g * 8),
                (AS3 void*)(Bs + (p * 64 + wave * 16) * 32), 16, 0, 0);
        }
        __syncthreads();
        s16x8 af[4], bfr[4];
        #pragma unroll
        for (int mt = 0; mt < 4; ++mt) {
            const int r = wr * 64 + mt * 16 + l15;
            af[mt] = *(const s16x8*)(As + r * 32 + ((quad ^ (r & 3)) << 3));
        }
        #pragma unroll
        for (int nt = 0; nt < 4; ++nt) {
            const int r = wc * 64 + nt * 16 + l15;
            bfr[nt] = *(const s16x8*)(Bs + r * 32 + ((quad ^ (r & 3)) << 3));
        }
        #pragma unroll
        for (int mt = 0; mt < 4; ++mt)
            #pragma unroll
            for (int nt = 0; nt < 4; ++nt)
                acc[mt][nt] = __builtin_amdgcn_mfma_f32_16x16x32_bf16(af[mt], bfr[nt], acc[mt][nt], 0, 0, 0);
    }
    #pragma unroll
    for (int mt = 0; mt < 4; ++mt)
        #pragma unroll
        for (int nt = 0; nt < 4; ++nt)
            #pragma unroll
            for (int r = 0; r < 4; ++r) {
                const int row = bm0 + wr * 64 + mt * 16 + quad * 4 + r;
                const int col = bn0 + wc * 64 + nt * 16 + l15;
                storeOut(C + (size_t)row * Nn + col, acc[mt][nt][r]);
            }
}

// ---------------- fused per-head q/k RMS+RoPE + V transpose --------------------------
__global__ __launch_bounds__(256) void qkv_head(const u16* __restrict__ qkv,
                                                const void* __restrict__ pos,
                                                const void* __restrict__ qk_scale,
                                                u16* __restrict__ q_ws,
                                                u16* __restrict__ k_ws,
                                                u16* __restrict__ vtg,
                                                const int* __restrict__ flag) {
    const int isf32 = *flag;
    const int nh = blockIdx.y;
    const int n = nh >> 4, h = nh & 15;
    const int l0 = blockIdx.x * 64;
    const int tid = threadIdx.x;
    const int wave = tid >> 6, lane = tid & 63;

    const float qs = loadIn(qk_scale, h, isf32);
    const float s = __expf(0.5f * fminf(qs, 4.605170186f) - 1.039720771f);
    const float qmul = s * s * 0.125f * 1.44269504089f;
    const int j = lane & 31;
    const float t = (float)((j & 15) * 16 + h);
    const float freq = 3.14159265358979f * __expf(t * (2.302585093f / 256.f));
    const int pj = j >> 4;

    #pragma unroll 2
    for (int it = 0; it < 16; ++it) {
        const int l = l0 + wave * 16 + it;
        const int tok = n * 2048 + l;
        const u16* row = qkv + (size_t)tok * 3072;
        float qv = bf2f(row[h * 64 + lane]);
        float kv = bf2f(row[1024 + h * 64 + lane]);
        float q2 = qv * qv, k2 = kv * kv;
        #pragma unroll
        for (int m = 1; m < 64; m <<= 1) { q2 += __shfl_xor(q2, m, 64); k2 += __shfl_xor(k2, m, 64); }
        float qn = qv * rsqrtf(q2 * (1.f / 64.f) + 1e-6f) * qmul;
        float kn = kv * rsqrtf(k2 * (1.f / 64.f) + 1e-6f);
        const float p = loadIn(pos, tok * 2 + pj, isf32);
        const float th = p * freq;
        const float c = __cosf(th), sn = __sinf(th);
        const float pq = __shfl_xor(qn, 32, 64);
        const float pk = __shfl_xor(kn, 32, 64);
        float qr, kr;
        if (lane < 32) { qr = qn * c - pq * sn; kr = kn * c - pk * sn; }
        else           { qr = qn * c + pq * sn; kr = kn * c + pk * sn; }
        const size_t oidx = ((size_t)nh * 2048 + l) * 64 + lane;
        q_ws[oidx] = f2bf(qr);
        k_ws[oidx] = f2bf(kr);
    }

    __shared__ u16 tbuf[64][65];
    const u16* vsrc = qkv + (size_t)(n * 2048 + l0) * 3072 + 2048 + h * 64;
    #pragma unroll
    for (int it = 0; it < 16; ++it) {
        const int idx = it * 256 + tid;
        const int r = idx >> 6, c = idx & 63;
        tbuf[r][c] = vsrc[(size_t)r * 3072 + c];
    }
    __syncthreads();
    u16* dst = vtg + (size_t)nh * 131072 + l0;
    #pragma unroll
    for (int it = 0; it < 16; ++it) {
        const int idx = it * 256 + tid;
        const int er = idx >> 6, lc = idx & 63;
        dst[(size_t)er * 2048 + lc] = tbuf[lc][er];
    }
}

// ---------------- flash attention v7: wave owns 64 q (4 groups) ----------------------
// Grid (8 qb, 32 nh, 2 ks) = 512 blocks. q-tile 256, k-tile 64 dbuf, 16 iters/half.
// Every kf/vf b128 LDS read now feeds 4 MFMAs (was 2): LDS bytes/FLOP down 1.4x.
// LDS: Ks 16K + Vt 16K + Ps 4*64*72*2B = 36K -> 68.6 KB -> 2 blocks/CU.
// Fixed-shift softmax (acc init -15); split halves combine linearly in combine_o.
__global__ __launch_bounds__(256, 2) void attn7(const u16* __restrict__ Q,
                                                const u16* __restrict__ K,
                                                const u16* __restrict__ Vtg,
                                                float* __restrict__ Opart,
                                                float* __restrict__ lpart) {
    __shared__ u16 Ks[2][64 * 64];
    __shared__ u16 Vt[2][64 * 64];
    __shared__ u16 Ps[4][64 * 72];
    const int nh = blockIdx.y;
    const int q0 = blockIdx.x * 256;
    const int ks = blockIdx.z;
    const int kb0 = ks * 1024;
    const int tid = threadIdx.x;
    const int wave = tid >> 6, lane = tid & 63;
    const int l15 = lane & 15, quad = lane >> 4;
    const size_t hb = (size_t)nh * 2048 * 64;
    const u16* Vbase = Vtg + (size_t)nh * 131072;
    const int dr0 = tid >> 3;
    const int dd  = tid & 7;

    s16x8 qf[4][2];
    #pragma unroll
    for (int qg = 0; qg < 4; ++qg)
        #pragma unroll
        for (int kc = 0; kc < 2; ++kc)
            qf[qg][kc] = *(const s16x8*)(Q + hb + (size_t)(q0 + wave * 64 + qg * 16 + l15) * 64 + kc * 32 + quad * 8);

    f32x4 Oacc[4][4] = {};
    float lacc[4] = {0.f, 0.f, 0.f, 0.f};
    u16* Pw = Ps[wave];

    // preload tile 0 of this half
    #pragma unroll
    for (int it = 0; it < 2; ++it) {
        const int row = it * 32 + dr0;
        const int g = dd ^ (row & 7);
        __builtin_amdgcn_global_load_lds(
            (const AS1 void*)(K + hb + (size_t)(kb0 + row) * 64 + g * 8),
            (AS3 void*)(Ks[0] + (it * 256 + wave * 64) * 8), 16, 0, 0);
        __builtin_amdgcn_global_load_lds(
            (const AS1 void*)(Vbase + (size_t)row * 2048 + kb0 + g * 8),
            (AS3 void*)(Vt[0] + (it * 256 + wave * 64) * 8), 16, 0, 0);
    }
    __syncthreads();

    for (int i = 0; i < 16; ++i) {
        const int cur = i & 1;
        const int kb = kb0 + i * 64;
        if (i < 15) {
            const int nxt = cur ^ 1;
            const int kbn = kb + 64;
            #pragma unroll
            for (int it = 0; it < 2; ++it) {
                const int row = it * 32 + dr0;
                const int g = dd ^ (row & 7);
                __builtin_amdgcn_global_load_lds(
                    (const AS1 void*)(K + hb + (size_t)(kbn + row) * 64 + g * 8),
                    (AS3 void*)(Ks[nxt] + (it * 256 + wave * 64) * 8), 16, 0, 0);
                __builtin_amdgcn_global_load_lds(
                    (const AS1 void*)(Vbase + (size_t)row * 2048 + kbn + g * 8),
                    (AS3 void*)(Vt[nxt] + (it * 256 + wave * 64) * 8), 16, 0, 0);
            }
        }

        // S^T = K * Q^T, acc init -15 (fixed softmax shift folded)
        f32x4 S[4][4];
        #pragma unroll
        for (int qg = 0; qg < 4; ++qg)
            #pragma unroll
            for (int kt = 0; kt < 4; ++kt) {
                S[qg][kt][0] = -15.f; S[qg][kt][1] = -15.f;
                S[qg][kt][2] = -15.f; S[qg][kt][3] = -15.f;
            }
        #pragma unroll
        for (int kt = 0; kt < 4; ++kt) {
            const int r = kt * 16 + l15;
            #pragma unroll
            for (int kc = 0; kc < 2; ++kc) {
                const s16x8 kf = *(const s16x8*)(Ks[cur] + r * 64 + (((kc * 4 + quad) ^ (r & 7)) << 3));
                #pragma unroll
                for (int qg = 0; qg < 4; ++qg)
                    S[qg][kt] = __builtin_amdgcn_mfma_f32_16x16x32_bf16(kf, qf[qg][kc], S[qg][kt], 0, 0, 0);
            }
        }

        // exp2, accumulate l, write P
        #pragma unroll
        for (int qg = 0; qg < 4; ++qg) {
            float rs = 0.f;
            #pragma unroll
            for (int kt = 0; kt < 4; ++kt) {
                const float e0 = fexp2(S[qg][kt][0]);
                const float e1 = fexp2(S[qg][kt][1]);
                const float e2 = fexp2(S[qg][kt][2]);
                const float e3 = fexp2(S[qg][kt][3]);
                rs += (e0 + e1) + (e2 + e3);
                u32x2 pk2;
                pk2[0] = pack_bf(e0, e1);
                pk2[1] = pack_bf(e2, e3);
                *(u32x2*)(Pw + (qg * 16 + l15) * 72 + kt * 16 + quad * 4) = pk2;
            }
            lacc[qg] += rs;
        }

        // PV: each vf read feeds 4 q-groups
        #pragma unroll
        for (int kc = 0; kc < 2; ++kc) {
            s16x8 pf[4];
            #pragma unroll
            for (int qg = 0; qg < 4; ++qg)
                pf[qg] = *(const s16x8*)(Pw + (qg * 16 + l15) * 72 + kc * 32 + quad * 8);
            #pragma unroll
            for (int nto = 0; nto < 4; ++nto) {
                const int e = nto * 16 + l15;
                const s16x8 vf = *(const s16x8*)(Vt[cur] + e * 64 + (((kc * 4 + quad) ^ (e & 7)) << 3));
                #pragma unroll
                for (int qg = 0; qg < 4; ++qg)
                    Oacc[qg][nto] = __builtin_amdgcn_mfma_f32_16x16x32_bf16(pf[qg], vf, Oacc[qg][nto], 0, 0, 0);
            }
        }

        if (i < 15) __syncthreads();
    }

    // l reduction across quads (q = l15)
    #pragma unroll
    for (int qg = 0; qg < 4; ++qg) {
        lacc[qg] += __shfl_xor(lacc[qg], 16, 64);
        lacc[qg] += __shfl_xor(lacc[qg], 32, 64);
    }

    const size_t pb = ((size_t)(ks * 32 + nh)) * 2048;
    if (quad == 0) {
        #pragma unroll
        for (int qg = 0; qg < 4; ++qg)
            lpart[pb + q0 + wave * 64 + qg * 16 + l15] = lacc[qg];
    }
    #pragma unroll
    for (int qg = 0; qg < 4; ++qg)
        #pragma unroll
        for (int r = 0; r < 4; ++r) {
            const int qrow = q0 + wave * 64 + qg * 16 + quad * 4 + r;
            float* orow = Opart + (pb + qrow) * 64;
            #pragma unroll
            for (int nto = 0; nto < 4; ++nto)
                orow[nto * 16 + l15] = Oacc[qg][nto][r];
        }
}

// ---------------- combine split-K partials -> bf16 O ---------------------------------
__global__ __launch_bounds__(256) void combine_o(const float* __restrict__ Opart,
                                                 const float* __restrict__ lpart,
                                                 u16* __restrict__ O) {
    constexpr size_t HS = (size_t)32 * 2048 * 64;
    constexpr size_t LS = (size_t)32 * 2048;
    const int tok = blockIdx.x;
    const int n = tok >> 11, l = tok & 2047;
    const int idx = threadIdx.x * 4;
    const int h = idx >> 6;
    const int nh = n * 16 + h;
    const size_t base = ((size_t)nh * 2048 + l) * 64 + (idx & 63);
    const float4 a = *(const float4*)(Opart + base);
    const float4 b = *(const float4*)(Opart + HS + base);
    const float inv = 1.f / (lpart[(size_t)nh * 2048 + l] + lpart[LS + (size_t)nh * 2048 + l]);
    u16* o = O + (size_t)tok * 1024 + idx;
    o[0] = f2bf((a.x + b.x) * inv);
    o[1] = f2bf((a.y + b.y) * inv);
    o[2] = f2bf((a.z + b.z) * inv);
    o[3] = f2bf((a.w + b.w) * inv);
}

// ---------------- launch --------------------------------------------------------------
extern "C" void kernel_launch(void* const* d_in, const int* in_sizes, int n_in,
                              void* d_out, int out_size, void* d_ws, size_t ws_size,
                              hipStream_t stream) {
    const void* x        = d_in[0];
    const void* pos      = d_in[1];
    const void* cond     = d_in[2];
    const void* w_cond   = d_in[3];
    const void* w_qkv    = d_in[4];
    const void* qk_scale = d_in[5];
    const void* w_out    = d_in[6];

    char* ws = (char*)d_ws;
    constexpr size_t MB = 1048576;
    constexpr size_t OFS_SCALE = 0;
    constexpr size_t OFS_FLAG  = 8192;
    constexpr size_t OFS_WOUTT = 16384;                  // 2 MB (live to end)
    constexpr size_t OFS_Q     = OFS_WOUTT + 2 * MB;     // 8 MB
    constexpr size_t OFS_K     = OFS_Q     + 8 * MB;     // 8 MB
    constexpr size_t OFS_VT    = OFS_K     + 8 * MB;     // 8 MB
    constexpr size_t OFS_O     = OFS_VT    + 8 * MB;     // 8 MB
    constexpr size_t OFS_XN    = OFS_O     + 8 * MB;     // 8 MB  -- dead after QKV gemm
    constexpr size_t OFS_WQKVT = OFS_XN    + 8 * MB;     // 6 MB  -- dead after QKV gemm
    constexpr size_t OFS_QKV   = OFS_WQKVT + 6 * MB;     // 24 MB -- dead after qkv_head
    constexpr size_t OFS_OPART = OFS_XN;                 // 32 MB f32 (aliases dead region)
    constexpr size_t OFS_LPART = OFS_OPART + 32 * MB;    // 512 KB f32

    float* scale = (float*)(ws + OFS_SCALE);
    int*   flag  = (int*)(ws + OFS_FLAG);
    u16* xn    = (u16*)(ws + OFS_XN);
    u16* wqkvT = (u16*)(ws + OFS_WQKVT);
    u16* woutT = (u16*)(ws + OFS_WOUTT);
    u16* qkv   = (u16*)(ws + OFS_QKV);
    u16* qws   = (u16*)(ws + OFS_Q);
    u16* kws   = (u16*)(ws + OFS_K);
    u16* vtg   = (u16*)(ws + OFS_VT);
    u16* ows   = (u16*)(ws + OFS_O);
    float* opart = (float*)(ws + OFS_OPART);
    float* lpart = (float*)(ws + OFS_LPART);

    detect_dtype<<<dim3(1), 256, 0, stream>>>((const u16*)x, flag);
    hipMemsetAsync(scale, 0, 2 * 1024 * sizeof(float), stream);
    cond_gemv<<<dim3(4, 2, 16), 256, 0, stream>>>(cond, w_cond, scale, flag);
    rmsnorm_x<<<dim3(4096), 256, 0, stream>>>(x, scale, xn, flag);
    transpose_bf<<<dim3(96, 32), 256, 0, stream>>>(w_qkv, wqkvT, 1024, 3072, flag);
    transpose_bf<<<dim3(32, 32), 256, 0, stream>>>(w_out, woutT, 1024, 1024, flag);
    gemm_bt<u16><<<dim3(24, 32), 256, 0, stream>>>(xn, wqkvT, qkv, 3072, 1024);
    qkv_head<<<dim3(32, 32), 256, 0, stream>>>(qkv, pos, qk_scale, qws, kws, vtg, flag);
    attn7<<<dim3(8, 32, 2), 256, 0, stream>>>(qws, kws, vtg, opart, lpart);
    combine_o<<<dim3(4096), 256, 0, stream>>>(opart, lpart, ows);
    gemm_bt<float><<<dim3(8, 32), 256, 0, stream>>>(ows, woutT, (float*)d_out, 1024, 1024);
}

// Round 10
// 242.751 us; speedup vs baseline: 1.0223x; 1.0223x over previous
//
#include <hip/hip_runtime.h>

typedef unsigned short u16;
typedef unsigned int u32;
typedef short s16x8 __attribute__((ext_vector_type(8)));
typedef short s16x4 __attribute__((ext_vector_type(4)));
typedef float f32x4 __attribute__((ext_vector_type(4)));
typedef u32 u32x2 __attribute__((ext_vector_type(2)));

#define AS1 __attribute__((address_space(1)))
#define AS3 __attribute__((address_space(3)))

__device__ __forceinline__ float bf2f(u16 u) {
    union { unsigned int i; float f; } x; x.i = ((unsigned int)u) << 16; return x.f;
}
__device__ __forceinline__ u16 f2bf(float f) {
    union { float f; unsigned int i; } x; x.f = f;
    unsigned int r = (x.i + 0x7FFFu + ((x.i >> 16) & 1u)) >> 16;
    return (u16)r;
}
__device__ __forceinline__ void storeOut(u16* p, float v) { *p = f2bf(v); }
__device__ __forceinline__ void storeOut(float* p, float v) { *p = v; }
__device__ __forceinline__ float loadIn(const void* p, size_t i, int isf32) {
    return isf32 ? ((const float*)p)[i] : bf2f(((const u16*)p)[i]);
}
__device__ __forceinline__ float fexp2(float x) {
#if __has_builtin(__builtin_amdgcn_exp2f)
    return __builtin_amdgcn_exp2f(x);
#else
    return exp2f(x);
#endif
}
__device__ __forceinline__ u32 pack_bf(float a, float b) {
    u32 ua = __float_as_uint(a) + 0x8000u;
    u32 ub = __float_as_uint(b) + 0x8000u;
    return __builtin_amdgcn_perm(ub, ua, 0x07060302u);
}
// inline dtype detector: wave-redundant scan of x[0..1023]; returns 1 if f32 storage.
__device__ __forceinline__ int detect_f32(const u16* __restrict__ x) {
    const int lane = threadIdx.x & 63;
    int c = 0;
    #pragma unroll
    for (int i = 0; i < 16; ++i) {
        const u16 u = x[lane * 16 + i];
        const int e = (u >> 7) & 0xFF;
        c += (e >= 101 && e <= 135) ? 1 : 0;
    }
    #pragma unroll
    for (int m = 1; m < 64; m <<= 1) c += __shfl_xor(c, m, 64);
    return c < 800;
}

// ---------------- cond @ w_cond (split-K GEMV, atomicAdd into zeroed f32 ws) ----------
__global__ __launch_bounds__(256) void cond_gemv(const void* __restrict__ cond,
                                                 const void* __restrict__ w,
                                                 float* __restrict__ out,
                                                 const u16* __restrict__ xdet) {
    const int isf32 = detect_f32(xdet);
    const int d  = blockIdx.x * 256 + threadIdx.x;
    const int n  = blockIdx.y;
    const int k0 = blockIdx.z * 64;
    float acc = 0.f;
    #pragma unroll 8
    for (int k = 0; k < 64; ++k)
        acc += loadIn(cond, n * 1024 + k0 + k, isf32) *
               loadIn(w, (size_t)(k0 + k) * 1024 + d, isf32);
    atomicAdd(out + n * 1024 + d, acc);
}

// ---------------- RMS norm of x -------------------------------------------------------
__global__ __launch_bounds__(256) void rmsnorm_x(const void* __restrict__ x,
                                                 const float* __restrict__ scl,
                                                 u16* __restrict__ xn) {
    const int isf32 = detect_f32((const u16*)x);
    const int tok = blockIdx.x;
    const int n = tok >> 11;
    u16* orow = xn + (size_t)tok * 1024;
    const int base = threadIdx.x * 4;
    float f0, f1, f2, f3;
    if (isf32) {
        const float4 v = *(const float4*)((const float*)x + (size_t)tok * 1024 + base);
        f0 = v.x; f1 = v.y; f2 = v.z; f3 = v.w;
    } else {
        s16x4 uv = *(const s16x4*)((const u16*)x + (size_t)tok * 1024 + base);
        f0 = bf2f((u16)uv[0]); f1 = bf2f((u16)uv[1]); f2 = bf2f((u16)uv[2]); f3 = bf2f((u16)uv[3]);
    }
    float ss = f0 * f0 + f1 * f1 + f2 * f2 + f3 * f3;
    #pragma unroll
    for (int m = 1; m < 64; m <<= 1) ss += __shfl_xor(ss, m, 64);
    __shared__ float red[4];
    const int wave = threadIdx.x >> 6, lane = threadIdx.x & 63;
    if (lane == 0) red[wave] = ss;
    __syncthreads();
    float ms = (red[0] + red[1] + red[2] + red[3]) * (1.f / 1024.f);
    float rinv = rsqrtf(ms + 1e-6f);
    orow[base + 0] = f2bf(f0 * (scl[n * 1024 + base + 0] + 1.f) * rinv);
    orow[base + 1] = f2bf(f1 * (scl[n * 1024 + base + 1] + 1.f) * rinv);
    orow[base + 2] = f2bf(f2 * (scl[n * 1024 + base + 2] + 1.f) * rinv);
    orow[base + 3] = f2bf(f3 * (scl[n * 1024 + base + 3] + 1.f) * rinv);
}

// ---------------- both weight transposes in one launch -------------------------------
// z=0: w_qkv 1024x3072 (96 x-blocks); z=1: w_out 1024x1024 (32 x-blocks).
__global__ __launch_bounds__(256) void transpose_w(const void* __restrict__ wqkv,
                                                   const void* __restrict__ wout,
                                                   u16* __restrict__ dqkv,
                                                   u16* __restrict__ dout,
                                                   const u16* __restrict__ xdet) {
    const int z = blockIdx.z;
    if (z == 1 && blockIdx.x >= 32) return;
    const int isf32 = detect_f32(xdet);
    const void* src = z ? wout : wqkv;
    u16* dst = z ? dout : dqkv;
    const int C = z ? 1024 : 3072;
    const int R = 1024;
    __shared__ u16 t[32][33];
    const int c0 = blockIdx.x * 32, r0 = blockIdx.y * 32;
    const int tx = threadIdx.x & 31, ty = threadIdx.x >> 5;
    #pragma unroll
    for (int i = 0; i < 4; ++i)
        t[ty + i * 8][tx] = f2bf(loadIn(src, (size_t)(r0 + ty + i * 8) * C + c0 + tx, isf32));
    __syncthreads();
    #pragma unroll
    for (int i = 0; i < 4; ++i)
        dst[(size_t)(c0 + ty + i * 8) * R + r0 + tx] = t[tx][ty + i * 8];
}

// ---------------- bf16 GEMM 128x128, BK=32, double-buffered 1-barrier/iter -----------
template <typename OutT>
__global__ __launch_bounds__(256, 3) void gemm2(const u16* __restrict__ A,
                                                const u16* __restrict__ BT,
                                                OutT* __restrict__ C, int Nn, int K) {
    __shared__ u16 As[2][128 * 32];
    __shared__ u16 Bs[2][128 * 32];
    const int tid = threadIdx.x;
    const int wave = tid >> 6, lane = tid & 63;
    const int l15 = lane & 15, quad = lane >> 4;
    const int bm0 = blockIdx.y * 128, bn0 = blockIdx.x * 128;
    const int wr = wave >> 1, wc = wave & 1;
    f32x4 acc[4][4] = {};
    const int srow = lane >> 2;
    const int g = (lane & 3) ^ (srow & 3);
    // preload bk=0 into buffer 0
    #pragma unroll
    for (int p = 0; p < 2; ++p) {
        const int rowl = p * 64 + wave * 16 + srow;
        __builtin_amdgcn_global_load_lds(
            (const AS1 void*)(A + (size_t)(bm0 + rowl) * K + g * 8),
            (AS3 void*)(As[0] + (p * 64 + wave * 16) * 32), 16, 0, 0);
        __builtin_amdgcn_global_load_lds(
            (const AS1 void*)(BT + (size_t)(bn0 + rowl) * K + g * 8),
            (AS3 void*)(Bs[0] + (p * 64 + wave * 16) * 32), 16, 0, 0);
    }
    __syncthreads();
    const int iters = K >> 5;
    for (int it = 0; it < iters; ++it) {
        const int cur = it & 1;
        if (it + 1 < iters) {
            const int bkn = (it + 1) << 5;
            #pragma unroll
            for (int p = 0; p < 2; ++p) {
                const int rowl = p * 64 + wave * 16 + srow;
                __builtin_amdgcn_global_load_lds(
                    (const AS1 void*)(A + (size_t)(bm0 + rowl) * K + bkn + g * 8),
                    (AS3 void*)(As[cur ^ 1] + (p * 64 + wave * 16) * 32), 16, 0, 0);
                __builtin_amdgcn_global_load_lds(
                    (const AS1 void*)(BT + (size_t)(bn0 + rowl) * K + bkn + g * 8),
                    (AS3 void*)(Bs[cur ^ 1] + (p * 64 + wave * 16) * 32), 16, 0, 0);
            }
        }
        s16x8 af[4], bfr[4];
        #pragma unroll
        for (int mt = 0; mt < 4; ++mt) {
            const int r = wr * 64 + mt * 16 + l15;
            af[mt] = *(const s16x8*)(As[cur] + r * 32 + ((quad ^ (r & 3)) << 3));
        }
        #pragma unroll
        for (int nt = 0; nt < 4; ++nt) {
            const int r = wc * 64 + nt * 16 + l15;
            bfr[nt] = *(const s16x8*)(Bs[cur] + r * 32 + ((quad ^ (r & 3)) << 3));
        }
        #pragma unroll
        for (int mt = 0; mt < 4; ++mt)
            #pragma unroll
            for (int nt = 0; nt < 4; ++nt)
                acc[mt][nt] = __builtin_amdgcn_mfma_f32_16x16x32_bf16(af[mt], bfr[nt], acc[mt][nt], 0, 0, 0);
        if (it + 1 < iters) __syncthreads();
    }
    #pragma unroll
    for (int mt = 0; mt < 4; ++mt)
        #pragma unroll
        for (int nt = 0; nt < 4; ++nt)
            #pragma unroll
            for (int r = 0; r < 4; ++r) {
                const int row = bm0 + wr * 64 + mt * 16 + quad * 4 + r;
                const int col = bn0 + wc * 64 + nt * 16 + l15;
                storeOut(C + (size_t)row * Nn + col, acc[mt][nt][r]);
            }
}

// ---------------- bf16 GEMM 128x64, BK=32, double-buffered (narrow N, 2x blocks) -----
template <typename OutT>
__global__ __launch_bounds__(256, 3) void gemm2_64(const u16* __restrict__ A,
                                                   const u16* __restrict__ BT,
                                                   OutT* __restrict__ C, int Nn, int K) {
    __shared__ u16 As[2][128 * 32];
    __shared__ u16 Bs[2][64 * 32];
    const int tid = threadIdx.x;
    const int wave = tid >> 6, lane = tid & 63;
    const int l15 = lane & 15, quad = lane >> 4;
    const int bm0 = blockIdx.y * 128, bn0 = blockIdx.x * 64;
    f32x4 acc[2][4] = {};
    const int srow = lane >> 2;
    const int g = (lane & 3) ^ (srow & 3);
    #pragma unroll
    for (int p = 0; p < 2; ++p) {
        const int rowl = p * 64 + wave * 16 + srow;
        __builtin_amdgcn_global_load_lds(
            (const AS1 void*)(A + (size_t)(bm0 + rowl) * K + g * 8),
            (AS3 void*)(As[0] + (p * 64 + wave * 16) * 32), 16, 0, 0);
    }
    __builtin_amdgcn_global_load_lds(
        (const AS1 void*)(BT + (size_t)(bn0 + wave * 16 + srow) * K + g * 8),
        (AS3 void*)(Bs[0] + (wave * 16) * 32), 16, 0, 0);
    __syncthreads();
    const int iters = K >> 5;
    for (int it = 0; it < iters; ++it) {
        const int cur = it & 1;
        if (it + 1 < iters) {
            const int bkn = (it + 1) << 5;
            #pragma unroll
            for (int p = 0; p < 2; ++p) {
                const int rowl = p * 64 + wave * 16 + srow;
                __builtin_amdgcn_global_load_lds(
                    (const AS1 void*)(A + (size_t)(bm0 + rowl) * K + bkn + g * 8),
                    (AS3 void*)(As[cur ^ 1] + (p * 64 + wave * 16) * 32), 16, 0, 0);
            }
            __builtin_amdgcn_global_load_lds(
                (const AS1 void*)(BT + (size_t)(bn0 + wave * 16 + srow) * K + bkn + g * 8),
                (AS3 void*)(Bs[cur ^ 1] + (wave * 16) * 32), 16, 0, 0);
        }
        s16x8 af[2], bfr[4];
        #pragma unroll
        for (int mt = 0; mt < 2; ++mt) {
            const int r = wave * 32 + mt * 16 + l15;
            af[mt] = *(const s16x8*)(As[cur] + r * 32 + ((quad ^ (r & 3)) << 3));
        }
        #pragma unroll
        for (int nt = 0; nt < 4; ++nt) {
            const int r = nt * 16 + l15;
            bfr[nt] = *(const s16x8*)(Bs[cur] + r * 32 + ((quad ^ (r & 3)) << 3));
        }
        #pragma unroll
        for (int mt = 0; mt < 2; ++mt)
            #pragma unroll
            for (int nt = 0; nt < 4; ++nt)
                acc[mt][nt] = __builtin_amdgcn_mfma_f32_16x16x32_bf16(af[mt], bfr[nt], acc[mt][nt], 0, 0, 0);
        if (it + 1 < iters) __syncthreads();
    }
    #pragma unroll
    for (int mt = 0; mt < 2; ++mt)
        #pragma unroll
        for (int nt = 0; nt < 4; ++nt)
            #pragma unroll
            for (int r = 0; r < 4; ++r) {
                const int row = bm0 + wave * 32 + mt * 16 + quad * 4 + r;
                const int col = bn0 + nt * 16 + l15;
                storeOut(C + (size_t)row * Nn + col, acc[mt][nt][r]);
            }
}

// ---------------- fused per-head q/k RMS+RoPE + V transpose --------------------------
__global__ __launch_bounds__(256) void qkv_head(const u16* __restrict__ qkv,
                                                const void* __restrict__ pos,
                                                const void* __restrict__ qk_scale,
                                                u16* __restrict__ q_ws,
                                                u16* __restrict__ k_ws,
                                                u16* __restrict__ vtg,
                                                const u16* __restrict__ xdet) {
    const int isf32 = detect_f32(xdet);
    const int nh = blockIdx.y;
    const int n = nh >> 4, h = nh & 15;
    const int l0 = blockIdx.x * 64;
    const int tid = threadIdx.x;
    const int wave = tid >> 6, lane = tid & 63;

    const float qs = loadIn(qk_scale, h, isf32);
    const float s = __expf(0.5f * fminf(qs, 4.605170186f) - 1.039720771f);
    const float qmul = s * s * 0.125f * 1.44269504089f;
    const int j = lane & 31;
    const float t = (float)((j & 15) * 16 + h);
    const float freq = 3.14159265358979f * __expf(t * (2.302585093f / 256.f));
    const int pj = j >> 4;

    #pragma unroll 2
    for (int it = 0; it < 16; ++it) {
        const int l = l0 + wave * 16 + it;
        const int tok = n * 2048 + l;
        const u16* row = qkv + (size_t)tok * 3072;
        float qv = bf2f(row[h * 64 + lane]);
        float kv = bf2f(row[1024 + h * 64 + lane]);
        float q2 = qv * qv, k2 = kv * kv;
        #pragma unroll
        for (int m = 1; m < 64; m <<= 1) { q2 += __shfl_xor(q2, m, 64); k2 += __shfl_xor(k2, m, 64); }
        float qn = qv * rsqrtf(q2 * (1.f / 64.f) + 1e-6f) * qmul;
        float kn = kv * rsqrtf(k2 * (1.f / 64.f) + 1e-6f);
        const float p = loadIn(pos, tok * 2 + pj, isf32);
        const float th = p * freq;
        const float c = __cosf(th), sn = __sinf(th);
        const float pq = __shfl_xor(qn, 32, 64);
        const float pk = __shfl_xor(kn, 32, 64);
        float qr, kr;
        if (lane < 32) { qr = qn * c - pq * sn; kr = kn * c - pk * sn; }
        else           { qr = qn * c + pq * sn; kr = kn * c + pk * sn; }
        const size_t oidx = ((size_t)nh * 2048 + l) * 64 + lane;
        q_ws[oidx] = f2bf(qr);
        k_ws[oidx] = f2bf(kr);
    }

    __shared__ u16 tbuf[64][65];
    const u16* vsrc = qkv + (size_t)(n * 2048 + l0) * 3072 + 2048 + h * 64;
    #pragma unroll
    for (int it = 0; it < 16; ++it) {
        const int idx = it * 256 + tid;
        const int r = idx >> 6, c = idx & 63;
        tbuf[r][c] = vsrc[(size_t)r * 3072 + c];
    }
    __syncthreads();
    u16* dst = vtg + (size_t)nh * 131072 + l0;
    #pragma unroll
    for (int it = 0; it < 16; ++it) {
        const int idx = it * 256 + tid;
        const int er = idx >> 6, lc = idx & 63;
        dst[(size_t)er * 2048 + lc] = tbuf[lc][er];
    }
}

// ---------------- flash attention v7: wave owns 64 q (4 groups), split-K=2 -----------
__global__ __launch_bounds__(256, 2) void attn7(const u16* __restrict__ Q,
                                                const u16* __restrict__ K,
                                                const u16* __restrict__ Vtg,
                                                float* __restrict__ Opart,
                                                float* __restrict__ lpart) {
    __shared__ u16 Ks[2][64 * 64];
    __shared__ u16 Vt[2][64 * 64];
    __shared__ u16 Ps[4][64 * 72];
    const int nh = blockIdx.y;
    const int q0 = blockIdx.x * 256;
    const int ks = blockIdx.z;
    const int kb0 = ks * 1024;
    const int tid = threadIdx.x;
    const int wave = tid >> 6, lane = tid & 63;
    const int l15 = lane & 15, quad = lane >> 4;
    const size_t hb = (size_t)nh * 2048 * 64;
    const u16* Vbase = Vtg + (size_t)nh * 131072;
    const int dr0 = tid >> 3;
    const int dd  = tid & 7;

    s16x8 qf[4][2];
    #pragma unroll
    for (int qg = 0; qg < 4; ++qg)
        #pragma unroll
        for (int kc = 0; kc < 2; ++kc)
            qf[qg][kc] = *(const s16x8*)(Q + hb + (size_t)(q0 + wave * 64 + qg * 16 + l15) * 64 + kc * 32 + quad * 8);

    f32x4 Oacc[4][4] = {};
    float lacc[4] = {0.f, 0.f, 0.f, 0.f};
    u16* Pw = Ps[wave];

    #pragma unroll
    for (int it = 0; it < 2; ++it) {
        const int row = it * 32 + dr0;
        const int g = dd ^ (row & 7);
        __builtin_amdgcn_global_load_lds(
            (const AS1 void*)(K + hb + (size_t)(kb0 + row) * 64 + g * 8),
            (AS3 void*)(Ks[0] + (it * 256 + wave * 64) * 8), 16, 0, 0);
        __builtin_amdgcn_global_load_lds(
            (const AS1 void*)(Vbase + (size_t)row * 2048 + kb0 + g * 8),
            (AS3 void*)(Vt[0] + (it * 256 + wave * 64) * 8), 16, 0, 0);
    }
    __syncthreads();

    for (int i = 0; i < 16; ++i) {
        const int cur = i & 1;
        const int kb = kb0 + i * 64;
        if (i < 15) {
            const int nxt = cur ^ 1;
            const int kbn = kb + 64;
            #pragma unroll
            for (int it = 0; it < 2; ++it) {
                const int row = it * 32 + dr0;
                const int g = dd ^ (row & 7);
                __builtin_amdgcn_global_load_lds(
                    (const AS1 void*)(K + hb + (size_t)(kbn + row) * 64 + g * 8),
                    (AS3 void*)(Ks[nxt] + (it * 256 + wave * 64) * 8), 16, 0, 0);
                __builtin_amdgcn_global_load_lds(
                    (const AS1 void*)(Vbase + (size_t)row * 2048 + kbn + g * 8),
                    (AS3 void*)(Vt[nxt] + (it * 256 + wave * 64) * 8), 16, 0, 0);
            }
        }

        f32x4 S[4][4];
        #pragma unroll
        for (int qg = 0; qg < 4; ++qg)
            #pragma unroll
            for (int kt = 0; kt < 4; ++kt) {
                S[qg][kt][0] = -15.f; S[qg][kt][1] = -15.f;
                S[qg][kt][2] = -15.f; S[qg][kt][3] = -15.f;
            }
        #pragma unroll
        for (int kt = 0; kt < 4; ++kt) {
            const int r = kt * 16 + l15;
            #pragma unroll
            for (int kc = 0; kc < 2; ++kc) {
                const s16x8 kf = *(const s16x8*)(Ks[cur] + r * 64 + (((kc * 4 + quad) ^ (r & 7)) << 3));
                #pragma unroll
                for (int qg = 0; qg < 4; ++qg)
                    S[qg][kt] = __builtin_amdgcn_mfma_f32_16x16x32_bf16(kf, qf[qg][kc], S[qg][kt], 0, 0, 0);
            }
        }

        #pragma unroll
        for (int qg = 0; qg < 4; ++qg) {
            float rs = 0.f;
            #pragma unroll
            for (int kt = 0; kt < 4; ++kt) {
                const float e0 = fexp2(S[qg][kt][0]);
                const float e1 = fexp2(S[qg][kt][1]);
                const float e2 = fexp2(S[qg][kt][2]);
                const float e3 = fexp2(S[qg][kt][3]);
                rs += (e0 + e1) + (e2 + e3);
                u32x2 pk2;
                pk2[0] = pack_bf(e0, e1);
                pk2[1] = pack_bf(e2, e3);
                *(u32x2*)(Pw + (qg * 16 + l15) * 72 + kt * 16 + quad * 4) = pk2;
            }
            lacc[qg] += rs;
        }

        #pragma unroll
        for (int kc = 0; kc < 2; ++kc) {
            s16x8 pf[4];
            #pragma unroll
            for (int qg = 0; qg < 4; ++qg)
                pf[qg] = *(const s16x8*)(Pw + (qg * 16 + l15) * 72 + kc * 32 + quad * 8);
            #pragma unroll
            for (int nto = 0; nto < 4; ++nto) {
                const int e = nto * 16 + l15;
                const s16x8 vf = *(const s16x8*)(Vt[cur] + e * 64 + (((kc * 4 + quad) ^ (e & 7)) << 3));
                #pragma unroll
                for (int qg = 0; qg < 4; ++qg)
                    Oacc[qg][nto] = __builtin_amdgcn_mfma_f32_16x16x32_bf16(pf[qg], vf, Oacc[qg][nto], 0, 0, 0);
            }
        }

        if (i < 15) __syncthreads();
    }

    #pragma unroll
    for (int qg = 0; qg < 4; ++qg) {
        lacc[qg] += __shfl_xor(lacc[qg], 16, 64);
        lacc[qg] += __shfl_xor(lacc[qg], 32, 64);
    }

    const size_t pb = ((size_t)(ks * 32 + nh)) * 2048;
    if (quad == 0) {
        #pragma unroll
        for (int qg = 0; qg < 4; ++qg)
            lpart[pb + q0 + wave * 64 + qg * 16 + l15] = lacc[qg];
    }
    #pragma unroll
    for (int qg = 0; qg < 4; ++qg)
        #pragma unroll
        for (int r = 0; r < 4; ++r) {
            const int qrow = q0 + wave * 64 + qg * 16 + quad * 4 + r;
            float* orow = Opart + (pb + qrow) * 64;
            #pragma unroll
            for (int nto = 0; nto < 4; ++nto)
                orow[nto * 16 + l15] = Oacc[qg][nto][r];
        }
}

// ---------------- combine split-K partials -> bf16 O ---------------------------------
__global__ __launch_bounds__(256) void combine_o(const float* __restrict__ Opart,
                                                 const float* __restrict__ lpart,
                                                 u16* __restrict__ O) {
    constexpr size_t HS = (size_t)32 * 2048 * 64;
    constexpr size_t LS = (size_t)32 * 2048;
    const int tok = blockIdx.x;
    const int n = tok >> 11, l = tok & 2047;
    const int idx = threadIdx.x * 4;
    const int h = idx >> 6;
    const int nh = n * 16 + h;
    const size_t base = ((size_t)nh * 2048 + l) * 64 + (idx & 63);
    const float4 a = *(const float4*)(Opart + base);
    const float4 b = *(const float4*)(Opart + HS + base);
    const float inv = 1.f / (lpart[(size_t)nh * 2048 + l] + lpart[LS + (size_t)nh * 2048 + l]);
    u16* o = O + (size_t)tok * 1024 + idx;
    o[0] = f2bf((a.x + b.x) * inv);
    o[1] = f2bf((a.y + b.y) * inv);
    o[2] = f2bf((a.z + b.z) * inv);
    o[3] = f2bf((a.w + b.w) * inv);
}

// ---------------- launch --------------------------------------------------------------
extern "C" void kernel_launch(void* const* d_in, const int* in_sizes, int n_in,
                              void* d_out, int out_size, void* d_ws, size_t ws_size,
                              hipStream_t stream) {
    const void* x        = d_in[0];
    const void* pos      = d_in[1];
    const void* cond     = d_in[2];
    const void* w_cond   = d_in[3];
    const void* w_qkv    = d_in[4];
    const void* qk_scale = d_in[5];
    const void* w_out    = d_in[6];
    const u16* xdet = (const u16*)x;

    char* ws = (char*)d_ws;
    constexpr size_t MB = 1048576;
    constexpr size_t OFS_SCALE = 0;
    constexpr size_t OFS_WOUTT = 16384;                  // 2 MB (live to end)
    constexpr size_t OFS_Q     = OFS_WOUTT + 2 * MB;     // 8 MB
    constexpr size_t OFS_K     = OFS_Q     + 8 * MB;     // 8 MB
    constexpr size_t OFS_VT    = OFS_K     + 8 * MB;     // 8 MB
    constexpr size_t OFS_O     = OFS_VT    + 8 * MB;     // 8 MB
    constexpr size_t OFS_XN    = OFS_O     + 8 * MB;     // 8 MB  -- dead after QKV gemm
    constexpr size_t OFS_WQKVT = OFS_XN    + 8 * MB;     // 6 MB  -- dead after QKV gemm
    constexpr size_t OFS_QKV   = OFS_WQKVT + 6 * MB;     // 24 MB -- dead after qkv_head
    constexpr size_t OFS_OPART = OFS_XN;                 // 32 MB f32 (aliases dead region)
    constexpr size_t OFS_LPART = OFS_OPART + 32 * MB;    // 512 KB f32

    float* scale = (float*)(ws + OFS_SCALE);
    u16* xn    = (u16*)(ws + OFS_XN);
    u16* wqkvT = (u16*)(ws + OFS_WQKVT);
    u16* woutT = (u16*)(ws + OFS_WOUTT);
    u16* qkv   = (u16*)(ws + OFS_QKV);
    u16* qws   = (u16*)(ws + OFS_Q);
    u16* kws   = (u16*)(ws + OFS_K);
    u16* vtg   = (u16*)(ws + OFS_VT);
    u16* ows   = (u16*)(ws + OFS_O);
    float* opart = (float*)(ws + OFS_OPART);
    float* lpart = (float*)(ws + OFS_LPART);

    hipMemsetAsync(scale, 0, 2 * 1024 * sizeof(float), stream);
    cond_gemv<<<dim3(4, 2, 16), 256, 0, stream>>>(cond, w_cond, scale, xdet);
    rmsnorm_x<<<dim3(4096), 256, 0, stream>>>(x, scale, xn);
    transpose_w<<<dim3(96, 32, 2), 256, 0, stream>>>(w_qkv, w_out, wqkvT, woutT, xdet);
    gemm2<u16><<<dim3(24, 32), 256, 0, stream>>>(xn, wqkvT, qkv, 3072, 1024);
    qkv_head<<<dim3(32, 32), 256, 0, stream>>>(qkv, pos, qk_scale, qws, kws, vtg, xdet);
    attn7<<<dim3(8, 32, 2), 256, 0, stream>>>(qws, kws, vtg, opart, lpart);
    combine_o<<<dim3(4096), 256, 0, stream>>>(opart, lpart, ows);
    gemm2_64<float><<<dim3(16, 32), 256, 0, stream>>>(ows, woutT, (float*)d_out, 1024, 1024);
}